// Round 6
// baseline (232.493 us; speedup 1.0000x reference)
//
#include <hip/hip_runtime.h>

typedef unsigned short u16;
typedef unsigned int u32;
typedef __attribute__((ext_vector_type(8))) __bf16 bf16x8;
typedef __attribute__((ext_vector_type(4))) float f32x4;

#define B_SZ   2
#define S_LEN  2048
#define E_DIM  1024
#define NHEAD  16
#define HD     64
#define KDIM   1024
#define NOUT   4096

__device__ __forceinline__ float bf2f(u16 u){
  union { u32 i; float f; } c; c.i = ((u32)u) << 16; return c.f;
}
__device__ __forceinline__ u16 f2bf(float f){
  union { float f; u32 i; } c; c.f = f;
  return (u16)((c.i + 0x7FFFu + ((c.i >> 16) & 1u)) >> 16);
}
__device__ __forceinline__ u16 f2bf_fast(float f){
  union { float f; u32 i; } c; c.f = f;
  return (u16)((c.i + 0x8000u) >> 16);
}
__device__ __forceinline__ void gl2lds16(const void* g, void* l){
  __builtin_amdgcn_global_load_lds((const __attribute__((address_space(1))) void*)g,
                                   (__attribute__((address_space(3))) void*)l, 16, 0, 0);
}

// ---------------- cast x: fp32 -> bf16, tile-swizzled ----------------
__global__ __launch_bounds__(256) void castx_kernel(const float* __restrict__ x, u16* __restrict__ xb){
  size_t flat = ((size_t)blockIdx.x * 256 + threadIdx.x) * 16;
  int m7 = (int)((flat >> 10) & 7);
  int cb = (int)((flat >> 3) & 7);
  size_t tile = flat & ~(size_t)63;
  float f[16];
  #pragma unroll
  for (int c = 0; c < 4; c++) *(float4*)&f[c * 4] = *(const float4*)&x[flat + c * 4];
  u16 o[16];
  #pragma unroll
  for (int i = 0; i < 16; i++) o[i] = f2bf(f[i]);
  *(uint4*)&xb[tile + ((cb ^ m7) * 8)]       = *(uint4*)&o[0];
  *(uint4*)&xb[tile + (((cb + 1) ^ m7) * 8)] = *(uint4*)&o[8];
}

// ---------------- W transpose + cast, swizzled ----------------
__global__ __launch_bounds__(256) void wtrans_kernel(const float* __restrict__ Wq, const float* __restrict__ Wk,
                                                     const float* __restrict__ Wv, const float* __restrict__ Wg,
                                                     u16* __restrict__ WT){
  const float* Ws[4] = {Wq, Wk, Wv, Wg};
  const float* W = Ws[blockIdx.z];
  int n0 = blockIdx.x * 64, k0 = blockIdx.y * 64;
  __shared__ u16 tile[64][66];
  int t = threadIdx.x;
  int r = t >> 2, cg = (t & 3) * 16;
  const float* src = W + (size_t)(k0 + r) * E_DIM + n0 + cg;
  float f[16];
  #pragma unroll
  for (int c = 0; c < 4; c++) *(float4*)&f[c * 4] = *(const float4*)&src[c * 4];
  #pragma unroll
  for (int i = 0; i < 16; i++) tile[r][cg + i] = f2bf(f[i]);
  __syncthreads();
  u16 ov[16];
  #pragma unroll
  for (int i = 0; i < 16; i++) ov[i] = tile[cg + i][r];
  int n7 = r & 7, cb = cg >> 3;
  u16* dst = WT + (size_t)(blockIdx.z * E_DIM + n0 + r) * KDIM + k0;
  *(uint4*)&dst[(cb ^ n7) * 8]       = *(uint4*)&ov[0];
  *(uint4*)&dst[((cb + 1) ^ n7) * 8] = *(uint4*)&ov[8];
}

// ---------------- fused QKVG GEMM + rotary/transpose epilogue ----------------
// zone = n0>>10: 0->qr (plain, rotated), 1->kr (swizzled, scaled+rotated),
// 2->vt (per-wave LDS transpose, swizzled), 3->gc (compacted).
__global__ __launch_bounds__(256) void gemm_kernel(const u16* __restrict__ A, const u16* __restrict__ Bt,
                                                   u16* __restrict__ qr, u16* __restrict__ kr,
                                                   u16* __restrict__ vt, u16* __restrict__ gc){
  __shared__ __align__(16) u16 smem[17408];   // As 8192 | Bs 8192 ; epilogue: 4 x (64x68)
  u16* As = smem;
  u16* Bs = smem + 8192;
  int m0 = blockIdx.y * 128, n0 = blockIdx.x * 128;
  int t = threadIdx.x;
  int wave = t >> 6, lane = t & 63;
  int l15 = lane & 15, quad = lane >> 4, h8 = lane & 7;
  int r0 = (wave & 1) * 64, c0 = (wave >> 1) * 64;
  f32x4 acc[4][4];
  #pragma unroll
  for (int i = 0; i < 4; i++)
    #pragma unroll
    for (int j = 0; j < 4; j++) acc[i][j] = (f32x4){0.f, 0.f, 0.f, 0.f};

  for (int k0 = 0; k0 < KDIM; k0 += 64){
    __syncthreads();
    #pragma unroll
    for (int c = 0; c < 4; c++){
      int L = c * 256 + t;
      gl2lds16(A + (size_t)(m0 + (L >> 3)) * KDIM + k0 + (L & 7) * 8, &As[L * 8]);
    }
    #pragma unroll
    for (int c = 0; c < 4; c++){
      int L = c * 256 + t;
      gl2lds16(Bt + (size_t)(n0 + (L >> 3)) * KDIM + k0 + (L & 7) * 8, &Bs[L * 8]);
    }
    __syncthreads();
    #pragma unroll
    for (int kk = 0; kk < 2; kk++){
      bf16x8 a[4], b[4];
      #pragma unroll
      for (int i = 0; i < 4; i++) a[i] = *(const bf16x8*)&As[(r0 + i * 16 + l15) * 64 + ((kk * 4 + quad) ^ h8) * 8];
      #pragma unroll
      for (int j = 0; j < 4; j++) b[j] = *(const bf16x8*)&Bs[(c0 + j * 16 + l15) * 64 + ((kk * 4 + quad) ^ h8) * 8];
      #pragma unroll
      for (int i = 0; i < 4; i++)
        #pragma unroll
        for (int j = 0; j < 4; j++)
          acc[i][j] = __builtin_amdgcn_mfma_f32_16x16x32_bf16(a[i], b[j], acc[i][j], 0, 0, 0);
    }
  }

  int zone = n0 >> 10;
  int b = m0 >> 11;
  int sbase = (m0 & 2047) + r0;               // wave's within-seq token base

  if (zone == 3){
    // ---- g: compacted store (B,S,E) ----
    int ebase = (n0 & 1023) + c0;
    #pragma unroll
    for (int i = 0; i < 4; i++){
      int tok = m0 + r0 + i * 16 + quad * 4;
      #pragma unroll
      for (int j = 0; j < 4; j++){
        int e = ebase + j * 16 + l15;
        #pragma unroll
        for (int r = 0; r < 4; r++)
          gc[(size_t)(tok + r) * E_DIM + e] = f2bf(acc[i][j][r]);
      }
    }
  } else if (zone == 2){
    // ---- v: per-wave 64x64 transpose via LDS -> vt (bh,d,s) swizzled ----
    __syncthreads();                          // all waves done reading As/Bs
    u16* Tw = smem + wave * 4352;             // 64 rows x 68 stride
    #pragma unroll
    for (int i = 0; i < 4; i++)
      #pragma unroll
      for (int j = 0; j < 4; j++){
        int d = j * 16 + l15;
        u16 pk[4];
        #pragma unroll
        for (int r = 0; r < 4; r++) pk[r] = f2bf(acc[i][j][r]);
        *(uint2*)&Tw[d * 68 + i * 16 + quad * 4] = *(uint2*)pk;
      }
    __syncthreads();
    int h = ((n0 & 1023) >> 6) + (c0 >> 6);
    size_t bh = (size_t)b * 16 + h;
    int sgq = lane >> 4;
    #pragma unroll
    for (int it = 0; it < 4; it++){
      int dd = (lane & 15) + 16 * it;
      u16 ov[16];
      *(uint4*)&ov[0] = *(const uint4*)&Tw[dd * 68 + sgq * 16];
      *(uint4*)&ov[8] = *(const uint4*)&Tw[dd * 68 + sgq * 16 + 8];
      int s0 = sbase + sgq * 16;
      int d7 = dd & 7;
      int cb = (s0 & 63) >> 3;
      size_t vrow = (bh * HD + dd) * S_LEN + (s0 & ~63);
      *(uint4*)&vt[vrow + ((cb ^ d7) * 8)]       = *(uint4*)&ov[0];
      *(uint4*)&vt[vrow + (((cb + 1) ^ d7) * 8)] = *(uint4*)&ov[8];
    }
  } else {
    // ---- q/k: rotary theta-shift in registers, store rotated ----
    float scale = (zone == 1) ? 0.03125f : 1.0f;
    int h = ((n0 & 1023) >> 6) + (c0 >> 6);
    size_t bh = (size_t)b * 16 + h;
    float sgn = (l15 & 1) ? 1.0f : -1.0f;
    #pragma unroll
    for (int j = 0; j < 4; j++){
      int d = j * 16 + l15;
      float a = exp2f(-(float)(d >> 1) * (13.287712379549449f / 31.0f));
      #pragma unroll
      for (int i = 0; i < 4; i++){
        #pragma unroll
        for (int r = 0; r < 4; r++){
          int s = sbase + i * 16 + quad * 4 + r;
          float v = acc[i][j][r] * scale;
          float p = __shfl_xor(v, 1);
          float ang = (float)s * a;
          float sn = __sinf(ang), cs = __cosf(ang);
          float rv = fmaf(sgn * p, sn, v * cs);
          size_t base = (bh * S_LEN + s) * HD;
          if (zone == 0){
            qr[base + d] = f2bf(rv);
          } else {
            int cb = d >> 3, s7 = s & 7;
            kr[base + ((cb ^ s7) * 8) + (d & 7)] = f2bf(rv);
          }
        }
      }
    }
  }
}

// ---------------- retention (transpose world): S^T = K Q^T, O^T = V^T P^T ----------------
__global__ __launch_bounds__(256, 2) void retention_kernel(const u16* __restrict__ qr, const u16* __restrict__ kr,
                                                           const u16* __restrict__ vt,
                                                           float* __restrict__ pO, float* __restrict__ pBa){
  int bh = blockIdx.x;
  int qb = 15 - (int)blockIdx.y;
  int z  = blockIdx.z;
  int h = bh & 15;
  int q0 = qb * 128;
  __shared__ __align__(16) u16 Ks[64 * 64];
  __shared__ __align__(16) u16 Vs[64 * 64];
  __shared__ __align__(16) u16 Ps[128 * 72];
  int t = threadIdx.x, wave = t >> 6, lane = t & 63;
  int l15 = lane & 15, quad = lane >> 4, h8 = lane & 7;

  float decay = log1pf(-exp2f(-5.0f - (float)h));
  float negd = -decay;
  float estep = __expf(64.0f * negd);

  int qsE[2], rowb[2];
  #pragma unroll
  for (int e = 0; e < 2; e++){ rowb[e] = wave * 32 + e * 16; qsE[e] = q0 + rowb[e]; }

  bf16x8 qB[2][2];
  #pragma unroll
  for (int e = 0; e < 2; e++){
    size_t qrow = ((size_t)bh * S_LEN + qsE[e] + l15) * HD;
    qB[e][0] = *(const bf16x8*)&qr[qrow + quad * 8];
    qB[e][1] = *(const bf16x8*)&qr[qrow + 32 + quad * 8];
  }

  float win_f = 18.0f / negd;
  int win_i = (win_f > 2.1e9f) ? 0x7f000000 : (int)win_f;
  int z_lo = z ? (qb + 1) : 0;
  int z_hi = z ? (2 * qb + 1) : qb;
  int kb_lo = z_lo;
  {
    int jmin = q0 - win_i;
    if (jmin > z_lo * 64){ int wlo = jmin >> 6; kb_lo = wlo > z_lo ? wlo : z_lo; }
  }
  int k0s = kb_lo * 64;

  float em1d = expm1f(decay);
  float rfE[2]; int iE[2];
  #pragma unroll
  for (int e = 0; e < 2; e++){
    int i = qsE[e] + l15;
    iE[e] = i;
    float rowsum = expm1f((float)(i + 1) * decay) / em1d;
    rfE[e] = __expf((float)(i - k0s) * decay) * rsqrtf(rowsum);
  }
  float e1 = __expf(negd);
  float c16 = __expf(negd * 16.0f);
  float cbr[4];
  cbr[0] = __expf(negd * (float)(quad * 4));
  cbr[1] = cbr[0] * e1; cbr[2] = cbr[1] * e1; cbr[3] = cbr[2] * e1;

  f32x4 o[2][4];
  #pragma unroll
  for (int e = 0; e < 2; e++)
    #pragma unroll
    for (int dt = 0; dt < 4; dt++) o[e][dt] = (f32x4){0.f, 0.f, 0.f, 0.f};
  float babs[2] = {0.f, 0.f};

  const u16* krbh = kr + (size_t)bh * S_LEN * HD;
  const u16* vtbh = vt + (size_t)bh * HD * S_LEN;

  for (int kb = kb_lo; kb <= z_hi; kb++){
    int k0 = kb * 64;
    __syncthreads();
    #pragma unroll
    for (int c = 0; c < 2; c++){
      int L = c * 256 + t;
      gl2lds16(krbh + (size_t)k0 * HD + L * 8, &Ks[L * 8]);
    }
    #pragma unroll
    for (int c = 0; c < 2; c++){
      int L = c * 256 + t;
      gl2lds16(vtbh + (size_t)(L >> 3) * S_LEN + k0 + (L & 7) * 8, &Vs[L * 8]);
    }
    __syncthreads();

    bf16x8 kA0[4], kA1[4];
    #pragma unroll
    for (int ct = 0; ct < 4; ct++){
      int rw = (ct * 16 + l15) * 64;
      kA0[ct] = *(const bf16x8*)&Ks[rw + ((quad ^ h8) * 8)];
      kA1[ct] = *(const bf16x8*)&Ks[rw + (((quad + 4) ^ h8) * 8)];
    }
    #pragma unroll
    for (int e = 0; e < 2; e++){
      int qs = qsE[e];
      if (k0 <= qs + 15 && k0 + 63 >= qs - win_i){
        bool diag = (k0 + 64 > qs);
        float cf[4] = {cbr[0], cbr[1], cbr[2], cbr[3]};
        #pragma unroll
        for (int ct = 0; ct < 4; ct++){
          f32x4 zacc = (f32x4){0.f, 0.f, 0.f, 0.f};
          zacc = __builtin_amdgcn_mfma_f32_16x16x32_bf16(kA0[ct], qB[e][0], zacc, 0, 0, 0);
          zacc = __builtin_amdgcn_mfma_f32_16x16x32_bf16(kA1[ct], qB[e][1], zacc, 0, 0, 0);
          u16 pk[4];
          #pragma unroll
          for (int r = 0; r < 4; r++){
            float p = zacc[r] * (rfE[e] * cf[r]);
            if (diag && (k0 + ct * 16 + quad * 4 + r) > iE[e]) p = 0.f;
            babs[e] += fabsf(p);
            pk[r] = f2bf_fast(p);
            cf[r] *= c16;
          }
          u32 lo = (u32)pk[0] | ((u32)pk[1] << 16);
          u32 hi = (u32)pk[2] | ((u32)pk[3] << 16);
          *(uint2*)&Ps[(rowb[e] + l15) * 72 + ct * 16 + quad * 4] = make_uint2(lo, hi);
        }
      }
    }
    #pragma unroll
    for (int e = 0; e < 2; e++){
      int qs = qsE[e];
      if (k0 <= qs + 15 && k0 + 63 >= qs - win_i){
        bf16x8 pB0 = *(const bf16x8*)&Ps[(rowb[e] + l15) * 72 + quad * 8];
        bf16x8 pB1 = *(const bf16x8*)&Ps[(rowb[e] + l15) * 72 + 32 + quad * 8];
        #pragma unroll
        for (int dt = 0; dt < 4; dt++){
          int rw = (dt * 16 + l15) * 64;
          bf16x8 vA0 = *(const bf16x8*)&Vs[rw + ((quad ^ h8) * 8)];
          bf16x8 vA1 = *(const bf16x8*)&Vs[rw + (((quad + 4) ^ h8) * 8)];
          o[e][dt] = __builtin_amdgcn_mfma_f32_16x16x32_bf16(vA0, pB0, o[e][dt], 0, 0, 0);
          o[e][dt] = __builtin_amdgcn_mfma_f32_16x16x32_bf16(vA1, pB1, o[e][dt], 0, 0, 0);
        }
      }
    }
    #pragma unroll
    for (int e = 0; e < 2; e++) rfE[e] *= estep;
  }

  size_t slot = ((size_t)bh * 16 + qb) * 2 + z;
  float* po = pO + slot * (4 * 128 * 16);
  #pragma unroll
  for (int e = 0; e < 2; e++){
    float bsum = babs[e];
    bsum += __shfl_xor(bsum, 16);
    bsum += __shfl_xor(bsum, 32);
    if (quad == 0) pBa[slot * 128 + rowb[e] + l15] = bsum;
    #pragma unroll
    for (int dt = 0; dt < 4; dt++)
      *(float4*)&po[(dt * 128 + rowb[e] + l15) * 16 + quad * 4] = *(float4*)&o[e][dt];
  }
}

// ---------------- combine: sum partials, denom clip, RMS, SiLU(g) ----------------
__global__ __launch_bounds__(128) void combine_kernel(const float* __restrict__ pO, const float* __restrict__ pBa,
                                                      const u16* __restrict__ gc, float* __restrict__ out){
  int bh = blockIdx.x, qb = blockIdx.y;
  int b = bh >> 4, h = bh & 15;
  int i = threadIdx.x;
  int s = qb * 128 + i;
  size_t s2 = ((size_t)bh * 16 + qb) * 2;
  const float* p0 = pO + s2 * 8192;
  const float* p1 = p0 + 8192;
  float v[64];
  #pragma unroll
  for (int dt = 0; dt < 4; dt++)
    #pragma unroll
    for (int c = 0; c < 4; c++){
      float4 a  = *(const float4*)&p0[(dt * 128 + i) * 16 + c * 4];
      float4 bb = *(const float4*)&p1[(dt * 128 + i) * 16 + c * 4];
      int d = dt * 16 + c * 4;
      v[d + 0] = a.x + bb.x; v[d + 1] = a.y + bb.y;
      v[d + 2] = a.z + bb.z; v[d + 3] = a.w + bb.w;
    }
  float bsum = pBa[s2 * 128 + i] + pBa[(s2 + 1) * 128 + i];
  float dinv = 1.0f / fminf(fmaxf(bsum, 1.0f), 50000.0f);
  float ssq = 0.f;
  #pragma unroll
  for (int d = 0; d < 64; d++){ v[d] *= dinv; ssq += v[d] * v[d]; }
  float rms = rsqrtf(ssq * (1.0f / 64.0f) + 1e-6f);
  size_t gbase = ((size_t)b * S_LEN + s) * E_DIM + h * HD;
  u16 gu[64];
  #pragma unroll
  for (int c = 0; c < 8; c++) *(uint4*)&gu[c * 8] = *(const uint4*)&gc[gbase + c * 8];
  float ov[64];
  #pragma unroll
  for (int d = 0; d < 64; d++){
    float gv = bf2f(gu[d]);
    float sg = gv / (1.0f + __expf(-gv));
    ov[d] = v[d] * rms * sg;
  }
  float* obase = out + ((size_t)b * S_LEN + s) * E_DIM + h * HD;
  #pragma unroll
  for (int c = 0; c < 16; c++) *(float4*)&obase[c * 4] = *(float4*)&ov[c * 4];
}

extern "C" void kernel_launch(void* const* d_in, const int* in_sizes, int n_in,
                              void* d_out, int out_size, void* d_ws, size_t ws_size,
                              hipStream_t stream){
  const float* x  = (const float*)d_in[0];
  const float* Wq = (const float*)d_in[1];
  const float* Wk = (const float*)d_in[2];
  const float* Wv = (const float*)d_in[3];
  const float* Wg = (const float*)d_in[4];
  float* out = (float*)d_out;
  char* ws = (char*)d_ws;
  // ws layout (stream-ordered overlays), 64.5 MB total:
  //   [0,8M):   xb   (dead after gemm)  \
  //   [8,16M):  WT   (dead after gemm)   } -> pO partials [0,32M)
  //   [16,32M): (pO tail)               /
  //   [32,40M): qr   (written by gemm epilogue)
  //   [40,48M): kr
  //   [48,56M): vt
  //   [56,64M): gc
  //   [64,64.5M): pBa
  u16*   xb  = (u16*)(ws);
  u16*   WT  = (u16*)(ws + (8ull  << 20));
  float* pO  = (float*)(ws);
  u16*   qrp = (u16*)(ws + (32ull << 20));
  u16*   krp = (u16*)(ws + (40ull << 20));
  u16*   vtp = (u16*)(ws + (48ull << 20));
  u16*   gcp = (u16*)(ws + (56ull << 20));
  float* pBa = (float*)(ws + (64ull << 20));

  castx_kernel    <<<dim3(1024),       256, 0, stream>>>(x, xb);
  wtrans_kernel   <<<dim3(16, 16, 4),  256, 0, stream>>>(Wq, Wk, Wv, Wg, WT);
  gemm_kernel     <<<dim3(32, 32),     256, 0, stream>>>(xb, WT, qrp, krp, vtp, gcp);
  retention_kernel<<<dim3(32, 16, 2),  256, 0, stream>>>(qrp, krp, vtp, pO, pBa);
  combine_kernel  <<<dim3(32, 16),     128, 0, stream>>>(pO, pBa, gcp, out);
}

// Round 7
// 192.564 us; speedup vs baseline: 1.2074x; 1.2074x over previous
//
#include <hip/hip_runtime.h>

typedef unsigned short u16;
typedef unsigned int u32;
typedef __attribute__((ext_vector_type(8))) __bf16 bf16x8;
typedef __attribute__((ext_vector_type(4))) float f32x4;

#define B_SZ   2
#define S_LEN  2048
#define E_DIM  1024
#define NHEAD  16
#define HD     64
#define KDIM   1024
#define NQKV   3072

__device__ __forceinline__ float bf2f(u16 u){
  union { u32 i; float f; } c; c.i = ((u32)u) << 16; return c.f;
}
__device__ __forceinline__ u16 f2bf(float f){
  union { float f; u32 i; } c; c.f = f;
  return (u16)((c.i + 0x7FFFu + ((c.i >> 16) & 1u)) >> 16);
}
__device__ __forceinline__ u16 f2bf_fast(float f){
  union { float f; u32 i; } c; c.f = f;
  return (u16)((c.i + 0x8000u) >> 16);
}
__device__ __forceinline__ void gl2lds16(const void* g, void* l){
  __builtin_amdgcn_global_load_lds((const __attribute__((address_space(1))) void*)g,
                                   (__attribute__((address_space(3))) void*)l, 16, 0, 0);
}

// ---------------- cast x: fp32 -> bf16, tile-swizzled ----------------
__global__ __launch_bounds__(256) void castx_kernel(const float* __restrict__ x, u16* __restrict__ xb){
  size_t flat = ((size_t)blockIdx.x * 256 + threadIdx.x) * 16;
  int m7 = (int)((flat >> 10) & 7);
  int cb = (int)((flat >> 3) & 7);
  size_t tile = flat & ~(size_t)63;
  float f[16];
  #pragma unroll
  for (int c = 0; c < 4; c++) *(float4*)&f[c * 4] = *(const float4*)&x[flat + c * 4];
  u16 o[16];
  #pragma unroll
  for (int i = 0; i < 16; i++) o[i] = f2bf(f[i]);
  *(uint4*)&xb[tile + ((cb ^ m7) * 8)]       = *(uint4*)&o[0];
  *(uint4*)&xb[tile + (((cb + 1) ^ m7) * 8)] = *(uint4*)&o[8];
}

// ---------------- W transpose + cast, swizzled ----------------
__global__ __launch_bounds__(256) void wtrans_kernel(const float* __restrict__ Wq, const float* __restrict__ Wk,
                                                     const float* __restrict__ Wv, const float* __restrict__ Wg,
                                                     u16* __restrict__ WT){
  const float* Ws[4] = {Wq, Wk, Wv, Wg};
  const float* W = Ws[blockIdx.z];
  int n0 = blockIdx.x * 64, k0 = blockIdx.y * 64;
  __shared__ u16 tile[64][66];
  int t = threadIdx.x;
  int r = t >> 2, cg = (t & 3) * 16;
  const float* src = W + (size_t)(k0 + r) * E_DIM + n0 + cg;
  float f[16];
  #pragma unroll
  for (int c = 0; c < 4; c++) *(float4*)&f[c * 4] = *(const float4*)&src[c * 4];
  #pragma unroll
  for (int i = 0; i < 16; i++) tile[r][cg + i] = f2bf(f[i]);
  __syncthreads();
  u16 ov[16];
  #pragma unroll
  for (int i = 0; i < 16; i++) ov[i] = tile[cg + i][r];
  int n7 = r & 7, cb = cg >> 3;
  u16* dst = WT + (size_t)(blockIdx.z * E_DIM + n0 + r) * KDIM + k0;
  *(uint4*)&dst[(cb ^ n7) * 8]       = *(uint4*)&ov[0];
  *(uint4*)&dst[((cb + 1) ^ n7) * 8] = *(uint4*)&ov[8];
}

// ---------------- fused QKVG GEMM (bf16, swizzled LDS) ----------------
// C split at the store: zones 0-2 (q|k|v cols) -> qkv (B*S, 3072); zone 3 (g) -> gc (B*S, 1024).
__global__ __launch_bounds__(256) void gemm_kernel(const u16* __restrict__ A, const u16* __restrict__ Bt,
                                                   u16* __restrict__ qkv, u16* __restrict__ gc){
  __shared__ __align__(16) u16 As[128 * 64];
  __shared__ __align__(16) u16 Bs[128 * 64];
  int m0 = blockIdx.y * 128, n0 = blockIdx.x * 128;
  int t = threadIdx.x;
  int wave = t >> 6, lane = t & 63;
  int l15 = lane & 15, quad = lane >> 4, h8 = lane & 7;
  int r0 = (wave & 1) * 64, c0 = (wave >> 1) * 64;
  f32x4 acc[4][4];
  #pragma unroll
  for (int i = 0; i < 4; i++)
    #pragma unroll
    for (int j = 0; j < 4; j++) acc[i][j] = (f32x4){0.f, 0.f, 0.f, 0.f};

  for (int k0 = 0; k0 < KDIM; k0 += 64){
    __syncthreads();
    #pragma unroll
    for (int c = 0; c < 4; c++){
      int L = c * 256 + t;
      gl2lds16(A + (size_t)(m0 + (L >> 3)) * KDIM + k0 + (L & 7) * 8, &As[L * 8]);
    }
    #pragma unroll
    for (int c = 0; c < 4; c++){
      int L = c * 256 + t;
      gl2lds16(Bt + (size_t)(n0 + (L >> 3)) * KDIM + k0 + (L & 7) * 8, &Bs[L * 8]);
    }
    __syncthreads();
    #pragma unroll
    for (int kk = 0; kk < 2; kk++){
      bf16x8 a[4], b[4];
      #pragma unroll
      for (int i = 0; i < 4; i++) a[i] = *(const bf16x8*)&As[(r0 + i * 16 + l15) * 64 + ((kk * 4 + quad) ^ h8) * 8];
      #pragma unroll
      for (int j = 0; j < 4; j++) b[j] = *(const bf16x8*)&Bs[(c0 + j * 16 + l15) * 64 + ((kk * 4 + quad) ^ h8) * 8];
      #pragma unroll
      for (int i = 0; i < 4; i++)
        #pragma unroll
        for (int j = 0; j < 4; j++)
          acc[i][j] = __builtin_amdgcn_mfma_f32_16x16x32_bf16(a[i], b[j], acc[i][j], 0, 0, 0);
    }
  }
  if (n0 < 3072){
    #pragma unroll
    for (int i = 0; i < 4; i++){
      int row = m0 + r0 + i * 16 + quad * 4;
      #pragma unroll
      for (int j = 0; j < 4; j++){
        int col = n0 + c0 + j * 16 + l15;
        #pragma unroll
        for (int r = 0; r < 4; r++)
          qkv[(size_t)(row + r) * NQKV + col] = f2bf(acc[i][j][r]);
      }
    }
  } else {
    #pragma unroll
    for (int i = 0; i < 4; i++){
      int row = m0 + r0 + i * 16 + quad * 4;
      #pragma unroll
      for (int j = 0; j < 4; j++){
        int e = (n0 - 3072) + c0 + j * 16 + l15;
        #pragma unroll
        for (int r = 0; r < 4; r++)
          gc[(size_t)(row + r) * E_DIM + e] = f2bf(acc[i][j][r]);
      }
    }
  }
}

// ---------------- rotary shift + head-major transpose ----------------
// reads qkv (B*S, 3072); qr plain, kr swizzled (+E^-0.5), vt (bh,d,s) swizzled.
__global__ __launch_bounds__(256) void shift_kernel(const u16* __restrict__ qkv,
                                                    u16* __restrict__ qr, u16* __restrict__ kr,
                                                    u16* __restrict__ vt){
  int sb = blockIdx.x, bh = blockIdx.y;
  int s0 = sb * 64;
  int t = threadIdx.x;
  int sl = t >> 2, dg = (t & 3) * 16;
  int s = s0 + sl;
  int h = bh & 15;
  size_t token = (size_t)(bh >> 4) * S_LEN + s;
  size_t base = token * NQKV + h * HD + dg;
  u16 qv[16], kv[16], vv[16];
  *(uint4*)&qv[0] = *(const uint4*)&qkv[base];
  *(uint4*)&qv[8] = *(const uint4*)&qkv[base + 8];
  *(uint4*)&kv[0] = *(const uint4*)&qkv[base + 1024];
  *(uint4*)&kv[8] = *(const uint4*)&qkv[base + 1024 + 8];
  *(uint4*)&vv[0] = *(const uint4*)&qkv[base + 2048];
  *(uint4*)&vv[8] = *(const uint4*)&qkv[base + 2048 + 8];
  u16 qo[16], ko[16];
  #pragma unroll
  for (int i = 0; i < 8; i++){
    int dd = dg + 2 * i;
    float a = exp2f(-(float)(dd >> 1) * (13.287712379549449f / 31.0f));
    float ang = (float)s * a;
    float sn = sinf(ang), cs = cosf(ang);
    float qe = bf2f(qv[2 * i]), qd = bf2f(qv[2 * i + 1]);
    qo[2 * i]     = f2bf(qe * cs - qd * sn);
    qo[2 * i + 1] = f2bf(qd * cs + qe * sn);
    float ke = bf2f(kv[2 * i]) * 0.03125f, kd = bf2f(kv[2 * i + 1]) * 0.03125f;
    ko[2 * i]     = f2bf(ke * cs - kd * sn);
    ko[2 * i + 1] = f2bf(kd * cs + ke * sn);
  }
  size_t dsto = ((size_t)bh * S_LEN + s) * HD;
  *(uint4*)&qr[dsto + dg]     = *(uint4*)&qo[0];
  *(uint4*)&qr[dsto + dg + 8] = *(uint4*)&qo[8];
  int s7 = s & 7, cbk = dg >> 3;
  *(uint4*)&kr[dsto + ((cbk ^ s7) * 8)]       = *(uint4*)&ko[0];
  *(uint4*)&kr[dsto + (((cbk + 1) ^ s7) * 8)] = *(uint4*)&ko[8];
  __shared__ u16 vs[64][66];
  #pragma unroll
  for (int i = 0; i < 16; i++) vs[sl][dg + i] = vv[i];
  __syncthreads();
  int d = t >> 2, jg = (t & 3) * 16;
  u16 ov[16];
  #pragma unroll
  for (int i = 0; i < 16; i++) ov[i] = vs[jg + i][d];
  int d7 = d & 7, cbv = jg >> 3;
  size_t vrow = ((size_t)bh * HD + d) * S_LEN + s0;
  *(uint4*)&vt[vrow + ((cbv ^ d7) * 8)]       = *(uint4*)&ov[0];
  *(uint4*)&vt[vrow + (((cbv + 1) ^ d7) * 8)] = *(uint4*)&ov[8];
}

// ---------------- retention (transpose world): S^T = K Q^T, O^T = V^T P^T ----------------
// z in {0,1} splits kb range; partials stored bf16 (pO) + fp32 babs (pBa).
__global__ __launch_bounds__(256, 2) void retention_kernel(const u16* __restrict__ qr, const u16* __restrict__ kr,
                                                           const u16* __restrict__ vt,
                                                           u16* __restrict__ pO, float* __restrict__ pBa){
  int bh = blockIdx.x;
  int qb = 15 - (int)blockIdx.y;
  int z  = blockIdx.z;
  int h = bh & 15;
  int q0 = qb * 128;
  __shared__ __align__(16) u16 Ks[64 * 64];
  __shared__ __align__(16) u16 Vs[64 * 64];
  __shared__ __align__(16) u16 Ps[128 * 72];
  int t = threadIdx.x, wave = t >> 6, lane = t & 63;
  int l15 = lane & 15, quad = lane >> 4, h8 = lane & 7;

  float decay = log1pf(-exp2f(-5.0f - (float)h));
  float negd = -decay;
  float estep = __expf(64.0f * negd);

  int qsE[2], rowb[2];
  #pragma unroll
  for (int e = 0; e < 2; e++){ rowb[e] = wave * 32 + e * 16; qsE[e] = q0 + rowb[e]; }

  bf16x8 qB[2][2];
  #pragma unroll
  for (int e = 0; e < 2; e++){
    size_t qrow = ((size_t)bh * S_LEN + qsE[e] + l15) * HD;
    qB[e][0] = *(const bf16x8*)&qr[qrow + quad * 8];
    qB[e][1] = *(const bf16x8*)&qr[qrow + 32 + quad * 8];
  }

  float win_f = 11.0f / negd;                 // drop terms < e^-11 (~2e-5 relative)
  int win_i = (win_f > 2.1e9f) ? 0x7f000000 : (int)win_f;
  int z_lo = z ? (qb + 1) : 0;
  int z_hi = z ? (2 * qb + 1) : qb;
  int kb_lo = z_lo;
  {
    int jmin = q0 - win_i;
    if (jmin > z_lo * 64){ int wlo = jmin >> 6; kb_lo = wlo > z_lo ? wlo : z_lo; }
  }
  int k0s = kb_lo * 64;

  float em1d = expm1f(decay);
  float rfE[2]; int iE[2];
  #pragma unroll
  for (int e = 0; e < 2; e++){
    int i = qsE[e] + l15;
    iE[e] = i;
    float rowsum = expm1f((float)(i + 1) * decay) / em1d;
    rfE[e] = __expf((float)(i - k0s) * decay) * rsqrtf(rowsum);
  }
  float e1 = __expf(negd);
  float c16 = __expf(negd * 16.0f);
  float cbr[4];
  cbr[0] = __expf(negd * (float)(quad * 4));
  cbr[1] = cbr[0] * e1; cbr[2] = cbr[1] * e1; cbr[3] = cbr[2] * e1;

  f32x4 o[2][4];
  #pragma unroll
  for (int e = 0; e < 2; e++)
    #pragma unroll
    for (int dt = 0; dt < 4; dt++) o[e][dt] = (f32x4){0.f, 0.f, 0.f, 0.f};
  float babs[2] = {0.f, 0.f};

  const u16* krbh = kr + (size_t)bh * S_LEN * HD;
  const u16* vtbh = vt + (size_t)bh * HD * S_LEN;

  for (int kb = kb_lo; kb <= z_hi; kb++){
    int k0 = kb * 64;
    __syncthreads();
    #pragma unroll
    for (int c = 0; c < 2; c++){
      int L = c * 256 + t;
      gl2lds16(krbh + (size_t)k0 * HD + L * 8, &Ks[L * 8]);
    }
    #pragma unroll
    for (int c = 0; c < 2; c++){
      int L = c * 256 + t;
      gl2lds16(vtbh + (size_t)(L >> 3) * S_LEN + k0 + (L & 7) * 8, &Vs[L * 8]);
    }
    __syncthreads();

    bf16x8 kA0[4], kA1[4];
    #pragma unroll
    for (int ct = 0; ct < 4; ct++){
      int rw = (ct * 16 + l15) * 64;
      kA0[ct] = *(const bf16x8*)&Ks[rw + ((quad ^ h8) * 8)];
      kA1[ct] = *(const bf16x8*)&Ks[rw + (((quad + 4) ^ h8) * 8)];
    }
    #pragma unroll
    for (int e = 0; e < 2; e++){
      int qs = qsE[e];
      if (k0 <= qs + 15 && k0 + 63 >= qs - win_i){
        bool diag = (k0 + 64 > qs);
        float cf[4] = {cbr[0], cbr[1], cbr[2], cbr[3]};
        #pragma unroll
        for (int ct = 0; ct < 4; ct++){
          f32x4 zacc = (f32x4){0.f, 0.f, 0.f, 0.f};
          zacc = __builtin_amdgcn_mfma_f32_16x16x32_bf16(kA0[ct], qB[e][0], zacc, 0, 0, 0);
          zacc = __builtin_amdgcn_mfma_f32_16x16x32_bf16(kA1[ct], qB[e][1], zacc, 0, 0, 0);
          u16 pk[4];
          #pragma unroll
          for (int r = 0; r < 4; r++){
            float p = zacc[r] * (rfE[e] * cf[r]);
            if (diag && (k0 + ct * 16 + quad * 4 + r) > iE[e]) p = 0.f;
            babs[e] += fabsf(p);
            pk[r] = f2bf_fast(p);
            cf[r] *= c16;
          }
          u32 lo = (u32)pk[0] | ((u32)pk[1] << 16);
          u32 hi = (u32)pk[2] | ((u32)pk[3] << 16);
          *(uint2*)&Ps[(rowb[e] + l15) * 72 + ct * 16 + quad * 4] = make_uint2(lo, hi);
        }
      }
    }
    #pragma unroll
    for (int e = 0; e < 2; e++){
      int qs = qsE[e];
      if (k0 <= qs + 15 && k0 + 63 >= qs - win_i){
        bf16x8 pB0 = *(const bf16x8*)&Ps[(rowb[e] + l15) * 72 + quad * 8];
        bf16x8 pB1 = *(const bf16x8*)&Ps[(rowb[e] + l15) * 72 + 32 + quad * 8];
        #pragma unroll
        for (int dt = 0; dt < 4; dt++){
          int rw = (dt * 16 + l15) * 64;
          bf16x8 vA0 = *(const bf16x8*)&Vs[rw + ((quad ^ h8) * 8)];
          bf16x8 vA1 = *(const bf16x8*)&Vs[rw + (((quad + 4) ^ h8) * 8)];
          o[e][dt] = __builtin_amdgcn_mfma_f32_16x16x32_bf16(vA0, pB0, o[e][dt], 0, 0, 0);
          o[e][dt] = __builtin_amdgcn_mfma_f32_16x16x32_bf16(vA1, pB1, o[e][dt], 0, 0, 0);
        }
      }
    }
    #pragma unroll
    for (int e = 0; e < 2; e++) rfE[e] *= estep;
  }

  // partials: pO[slot][dt=4][i=128][dsub=16] bf16, pBa[slot][i=128] fp32
  size_t slot = ((size_t)bh * 16 + qb) * 2 + z;
  u16* po = pO + slot * (4 * 128 * 16);
  #pragma unroll
  for (int e = 0; e < 2; e++){
    float bsum = babs[e];
    bsum += __shfl_xor(bsum, 16);
    bsum += __shfl_xor(bsum, 32);
    if (quad == 0) pBa[slot * 128 + rowb[e] + l15] = bsum;
    #pragma unroll
    for (int dt = 0; dt < 4; dt++){
      u16 pk[4];
      #pragma unroll
      for (int r = 0; r < 4; r++) pk[r] = f2bf(o[e][dt][r]);
      *(uint2*)&po[(dt * 128 + rowb[e] + l15) * 16 + quad * 4] = *(uint2*)pk;
    }
  }
}

// ---------------- combine: sum partials, denom clip, RMS, SiLU(g) ----------------
__global__ __launch_bounds__(128) void combine_kernel(const u16* __restrict__ pO, const float* __restrict__ pBa,
                                                      const u16* __restrict__ gc, float* __restrict__ out){
  int bh = blockIdx.x, qb = blockIdx.y;
  int b = bh >> 4, h = bh & 15;
  int i = threadIdx.x;
  int s = qb * 128 + i;
  size_t s2 = ((size_t)bh * 16 + qb) * 2;
  const u16* p0 = pO + s2 * 8192;
  const u16* p1 = p0 + 8192;
  float v[64];
  #pragma unroll
  for (int dt = 0; dt < 4; dt++){
    u16 a[16], bb[16];
    *(uint4*)&a[0]  = *(const uint4*)&p0[(dt * 128 + i) * 16];
    *(uint4*)&a[8]  = *(const uint4*)&p0[(dt * 128 + i) * 16 + 8];
    *(uint4*)&bb[0] = *(const uint4*)&p1[(dt * 128 + i) * 16];
    *(uint4*)&bb[8] = *(const uint4*)&p1[(dt * 128 + i) * 16 + 8];
    #pragma unroll
    for (int c = 0; c < 16; c++) v[dt * 16 + c] = bf2f(a[c]) + bf2f(bb[c]);
  }
  float bsum = pBa[s2 * 128 + i] + pBa[(s2 + 1) * 128 + i];
  float dinv = 1.0f / fminf(fmaxf(bsum, 1.0f), 50000.0f);
  float ssq = 0.f;
  #pragma unroll
  for (int d = 0; d < 64; d++){ v[d] *= dinv; ssq += v[d] * v[d]; }
  float rms = rsqrtf(ssq * (1.0f / 64.0f) + 1e-6f);
  size_t gbase = ((size_t)b * S_LEN + s) * E_DIM + h * HD;
  u16 gu[64];
  #pragma unroll
  for (int c = 0; c < 8; c++) *(uint4*)&gu[c * 8] = *(const uint4*)&gc[gbase + c * 8];
  float ov[64];
  #pragma unroll
  for (int d = 0; d < 64; d++){
    float gv = bf2f(gu[d]);
    float sg = gv / (1.0f + __expf(-gv));
    ov[d] = v[d] * rms * sg;
  }
  float* obase = out + ((size_t)b * S_LEN + s) * E_DIM + h * HD;
  #pragma unroll
  for (int c = 0; c < 16; c++) *(float4*)&obase[c * 4] = *(float4*)&ov[c * 4];
}

extern "C" void kernel_launch(void* const* d_in, const int* in_sizes, int n_in,
                              void* d_out, int out_size, void* d_ws, size_t ws_size,
                              hipStream_t stream){
  const float* x  = (const float*)d_in[0];
  const float* Wq = (const float*)d_in[1];
  const float* Wk = (const float*)d_in[2];
  const float* Wv = (const float*)d_in[3];
  const float* Wg = (const float*)d_in[4];
  float* out = (float*)d_out;
  char* ws = (char*)d_ws;
  // ws layout (stream-ordered overlays), 56.5 MB total:
  //   [0,8M):   xb  (dead after gemm)  -> vt
  //   [8,16M):  WT  (dead after gemm)  -> qr
  //   [16,40M): qkv (dead after shift) -> pO bf16 partials [16,32M)
  //   [40,48M): gc  (gemm g output, live until combine)
  //   [48,56M): kr
  //   [56,56.5M): pBa
  u16*   xb  = (u16*)(ws);
  u16*   WT  = (u16*)(ws + (8ull  << 20));
  u16*   qkv = (u16*)(ws + (16ull << 20));
  u16*   gcp = (u16*)(ws + (40ull << 20));
  u16*   vtp = (u16*)(ws);
  u16*   qrp = (u16*)(ws + (8ull  << 20));
  u16*   pO  = (u16*)(ws + (16ull << 20));
  u16*   krp = (u16*)(ws + (48ull << 20));
  float* pBa = (float*)(ws + (56ull << 20));

  castx_kernel    <<<dim3(1024),       256, 0, stream>>>(x, xb);
  wtrans_kernel   <<<dim3(16, 16, 4),  256, 0, stream>>>(Wq, Wk, Wv, Wg, WT);
  gemm_kernel     <<<dim3(32, 32),     256, 0, stream>>>(xb, WT, qkv, gcp);
  shift_kernel    <<<dim3(32, 32),     256, 0, stream>>>(qkv, qrp, krp, vtp);
  retention_kernel<<<dim3(32, 16, 2),  256, 0, stream>>>(qrp, krp, vtp, pO, pBa);
  combine_kernel  <<<dim3(32, 16),     128, 0, stream>>>(pO, pBa, gcp, out);
}

// Round 8
// 188.352 us; speedup vs baseline: 1.2344x; 1.0224x over previous
//
#include <hip/hip_runtime.h>

typedef unsigned short u16;
typedef unsigned int u32;
typedef __attribute__((ext_vector_type(8))) __bf16 bf16x8;
typedef __attribute__((ext_vector_type(4))) float f32x4;

#define B_SZ   2
#define S_LEN  2048
#define E_DIM  1024
#define NHEAD  16
#define HD     64
#define KDIM   1024
#define NQKV   3072

__device__ __forceinline__ float bf2f(u16 u){
  union { u32 i; float f; } c; c.i = ((u32)u) << 16; return c.f;
}
__device__ __forceinline__ u16 f2bf(float f){
  union { float f; u32 i; } c; c.f = f;
  return (u16)((c.i + 0x7FFFu + ((c.i >> 16) & 1u)) >> 16);
}
__device__ __forceinline__ u16 f2bf_fast(float f){
  union { float f; u32 i; } c; c.f = f;
  return (u16)((c.i + 0x8000u) >> 16);
}
__device__ __forceinline__ void gl2lds16(const void* g, void* l){
  __builtin_amdgcn_global_load_lds((const __attribute__((address_space(1))) void*)g,
                                   (__attribute__((address_space(3))) void*)l, 16, 0, 0);
}

// ---------------- prep: z<4 -> W_z transpose+cast (swizzled); z>=4 -> x cast (swizzled) ----------------
__global__ __launch_bounds__(256) void prep_kernel(const float* __restrict__ x,
                                                   const float* __restrict__ Wq, const float* __restrict__ Wk,
                                                   const float* __restrict__ Wv, const float* __restrict__ Wg,
                                                   u16* __restrict__ xb, u16* __restrict__ WT){
  __shared__ u16 tile[64][66];
  int z = blockIdx.z;
  int t = threadIdx.x;
  if (z < 4){
    const float* Ws[4] = {Wq, Wk, Wv, Wg};
    const float* W = Ws[z];
    int n0 = blockIdx.x * 64, k0 = blockIdx.y * 64;
    int r = t >> 2, cg = (t & 3) * 16;
    const float* src = W + (size_t)(k0 + r) * E_DIM + n0 + cg;
    float f[16];
    #pragma unroll
    for (int c = 0; c < 4; c++) *(float4*)&f[c * 4] = *(const float4*)&src[c * 4];
    #pragma unroll
    for (int i = 0; i < 16; i++) tile[r][cg + i] = f2bf(f[i]);
    __syncthreads();
    u16 ov[16];
    #pragma unroll
    for (int i = 0; i < 16; i++) ov[i] = tile[cg + i][r];
    int n7 = r & 7, cb = cg >> 3;
    u16* dst = WT + (size_t)(z * E_DIM + n0 + r) * KDIM + k0;
    *(uint4*)&dst[(cb ^ n7) * 8]       = *(uint4*)&ov[0];
    *(uint4*)&dst[((cb + 1) ^ n7) * 8] = *(uint4*)&ov[8];
  } else {
    int blk = (z - 4) * 256 + blockIdx.y * 16 + blockIdx.x;
    size_t flat = ((size_t)blk * 256 + t) * 16;
    int m7 = (int)((flat >> 10) & 7);
    int cb = (int)((flat >> 3) & 7);
    size_t tl = flat & ~(size_t)63;
    float f[16];
    #pragma unroll
    for (int c = 0; c < 4; c++) *(float4*)&f[c * 4] = *(const float4*)&x[flat + c * 4];
    u16 o[16];
    #pragma unroll
    for (int i = 0; i < 16; i++) o[i] = f2bf(f[i]);
    *(uint4*)&xb[tl + ((cb ^ m7) * 8)]       = *(uint4*)&o[0];
    *(uint4*)&xb[tl + (((cb + 1) ^ m7) * 8)] = *(uint4*)&o[8];
  }
}

// ---------------- fused QKVG GEMM (bf16, swizzled LDS) ----------------
// C split at the store: zones 0-2 (q|k|v cols) -> qkv (B*S, 3072); zone 3 (g) -> gc (B*S, 1024).
__global__ __launch_bounds__(256) void gemm_kernel(const u16* __restrict__ A, const u16* __restrict__ Bt,
                                                   u16* __restrict__ qkv, u16* __restrict__ gc){
  __shared__ __align__(16) u16 As[128 * 64];
  __shared__ __align__(16) u16 Bs[128 * 64];
  int m0 = blockIdx.y * 128, n0 = blockIdx.x * 128;
  int t = threadIdx.x;
  int wave = t >> 6, lane = t & 63;
  int l15 = lane & 15, quad = lane >> 4, h8 = lane & 7;
  int r0 = (wave & 1) * 64, c0 = (wave >> 1) * 64;
  f32x4 acc[4][4];
  #pragma unroll
  for (int i = 0; i < 4; i++)
    #pragma unroll
    for (int j = 0; j < 4; j++) acc[i][j] = (f32x4){0.f, 0.f, 0.f, 0.f};

  for (int k0 = 0; k0 < KDIM; k0 += 64){
    __syncthreads();
    #pragma unroll
    for (int c = 0; c < 4; c++){
      int L = c * 256 + t;
      gl2lds16(A + (size_t)(m0 + (L >> 3)) * KDIM + k0 + (L & 7) * 8, &As[L * 8]);
    }
    #pragma unroll
    for (int c = 0; c < 4; c++){
      int L = c * 256 + t;
      gl2lds16(Bt + (size_t)(n0 + (L >> 3)) * KDIM + k0 + (L & 7) * 8, &Bs[L * 8]);
    }
    __syncthreads();
    #pragma unroll
    for (int kk = 0; kk < 2; kk++){
      bf16x8 a[4], b[4];
      #pragma unroll
      for (int i = 0; i < 4; i++) a[i] = *(const bf16x8*)&As[(r0 + i * 16 + l15) * 64 + ((kk * 4 + quad) ^ h8) * 8];
      #pragma unroll
      for (int j = 0; j < 4; j++) b[j] = *(const bf16x8*)&Bs[(c0 + j * 16 + l15) * 64 + ((kk * 4 + quad) ^ h8) * 8];
      #pragma unroll
      for (int i = 0; i < 4; i++)
        #pragma unroll
        for (int j = 0; j < 4; j++)
          acc[i][j] = __builtin_amdgcn_mfma_f32_16x16x32_bf16(a[i], b[j], acc[i][j], 0, 0, 0);
    }
  }
  if (n0 < 3072){
    #pragma unroll
    for (int i = 0; i < 4; i++){
      int row = m0 + r0 + i * 16 + quad * 4;
      #pragma unroll
      for (int j = 0; j < 4; j++){
        int col = n0 + c0 + j * 16 + l15;
        #pragma unroll
        for (int r = 0; r < 4; r++)
          qkv[(size_t)(row + r) * NQKV + col] = f2bf(acc[i][j][r]);
      }
    }
  } else {
    #pragma unroll
    for (int i = 0; i < 4; i++){
      int row = m0 + r0 + i * 16 + quad * 4;
      #pragma unroll
      for (int j = 0; j < 4; j++){
        int e = (n0 - 3072) + c0 + j * 16 + l15;
        #pragma unroll
        for (int r = 0; r < 4; r++)
          gc[(size_t)(row + r) * E_DIM + e] = f2bf(acc[i][j][r]);
      }
    }
  }
}

// ---------------- rotary shift + head-major transpose ----------------
__global__ __launch_bounds__(256) void shift_kernel(const u16* __restrict__ qkv,
                                                    u16* __restrict__ qr, u16* __restrict__ kr,
                                                    u16* __restrict__ vt){
  int sb = blockIdx.x, bh = blockIdx.y;
  int s0 = sb * 64;
  int t = threadIdx.x;
  int sl = t >> 2, dg = (t & 3) * 16;
  int s = s0 + sl;
  int h = bh & 15;
  size_t token = (size_t)(bh >> 4) * S_LEN + s;
  size_t base = token * NQKV + h * HD + dg;
  u16 qv[16], kv[16], vv[16];
  *(uint4*)&qv[0] = *(const uint4*)&qkv[base];
  *(uint4*)&qv[8] = *(const uint4*)&qkv[base + 8];
  *(uint4*)&kv[0] = *(const uint4*)&qkv[base + 1024];
  *(uint4*)&kv[8] = *(const uint4*)&qkv[base + 1024 + 8];
  *(uint4*)&vv[0] = *(const uint4*)&qkv[base + 2048];
  *(uint4*)&vv[8] = *(const uint4*)&qkv[base + 2048 + 8];
  u16 qo[16], ko[16];
  #pragma unroll
  for (int i = 0; i < 8; i++){
    int dd = dg + 2 * i;
    float a = exp2f(-(float)(dd >> 1) * (13.287712379549449f / 31.0f));
    float ang = (float)s * a;
    float sn = sinf(ang), cs = cosf(ang);
    float qe = bf2f(qv[2 * i]), qd = bf2f(qv[2 * i + 1]);
    qo[2 * i]     = f2bf(qe * cs - qd * sn);
    qo[2 * i + 1] = f2bf(qd * cs + qe * sn);
    float ke = bf2f(kv[2 * i]) * 0.03125f, kd = bf2f(kv[2 * i + 1]) * 0.03125f;
    ko[2 * i]     = f2bf(ke * cs - kd * sn);
    ko[2 * i + 1] = f2bf(kd * cs + ke * sn);
  }
  size_t dsto = ((size_t)bh * S_LEN + s) * HD;
  *(uint4*)&qr[dsto + dg]     = *(uint4*)&qo[0];
  *(uint4*)&qr[dsto + dg + 8] = *(uint4*)&qo[8];
  int s7 = s & 7, cbk = dg >> 3;
  *(uint4*)&kr[dsto + ((cbk ^ s7) * 8)]       = *(uint4*)&ko[0];
  *(uint4*)&kr[dsto + (((cbk + 1) ^ s7) * 8)] = *(uint4*)&ko[8];
  __shared__ u16 vs[64][66];
  #pragma unroll
  for (int i = 0; i < 16; i++) vs[sl][dg + i] = vv[i];
  __syncthreads();
  int d = t >> 2, jg = (t & 3) * 16;
  u16 ov[16];
  #pragma unroll
  for (int i = 0; i < 16; i++) ov[i] = vs[jg + i][d];
  int d7 = d & 7, cbv = jg >> 3;
  size_t vrow = ((size_t)bh * HD + d) * S_LEN + s0;
  *(uint4*)&vt[vrow + ((cbv ^ d7) * 8)]       = *(uint4*)&ov[0];
  *(uint4*)&vt[vrow + (((cbv + 1) ^ d7) * 8)] = *(uint4*)&ov[8];
}

// ---------------- retention (transpose world): S^T = K Q^T, O^T = V^T P^T ----------------
// 4-way kb split across blockIdx.z: z gets [z*nk/4, (z+1)*nk/4) of nk=2qb+2 tiles (window-clamped).
// Partials: pO bf16, pBa bf16.
__global__ __launch_bounds__(256, 2) void retention_kernel(const u16* __restrict__ qr, const u16* __restrict__ kr,
                                                           const u16* __restrict__ vt,
                                                           u16* __restrict__ pO, u16* __restrict__ pBa){
  int bh = blockIdx.x;
  int qb = 15 - (int)blockIdx.y;
  int z  = blockIdx.z;
  int h = bh & 15;
  int q0 = qb * 128;
  __shared__ __align__(16) u16 Ks[64 * 64];
  __shared__ __align__(16) u16 Vs[64 * 64];
  __shared__ __align__(16) u16 Ps[128 * 72];
  int t = threadIdx.x, wave = t >> 6, lane = t & 63;
  int l15 = lane & 15, quad = lane >> 4, h8 = lane & 7;

  float decay = log1pf(-exp2f(-5.0f - (float)h));
  float negd = -decay;
  float estep = __expf(64.0f * negd);

  int qsE[2], rowb[2];
  #pragma unroll
  for (int e = 0; e < 2; e++){ rowb[e] = wave * 32 + e * 16; qsE[e] = q0 + rowb[e]; }

  bf16x8 qB[2][2];
  #pragma unroll
  for (int e = 0; e < 2; e++){
    size_t qrow = ((size_t)bh * S_LEN + qsE[e] + l15) * HD;
    qB[e][0] = *(const bf16x8*)&qr[qrow + quad * 8];
    qB[e][1] = *(const bf16x8*)&qr[qrow + 32 + quad * 8];
  }

  float win_f = 11.0f / negd;
  int win_i = (win_f > 2.1e9f) ? 0x7f000000 : (int)win_f;
  int nk = 2 * qb + 2;
  int z_lo = (z * nk) >> 2;
  int z_hi = (((z + 1) * nk) >> 2) - 1;
  int kb_lo = z_lo;
  {
    int jmin = q0 - win_i;
    if (jmin > z_lo * 64){ int wlo = jmin >> 6; kb_lo = wlo > z_lo ? wlo : z_lo; }
  }
  int k0s = kb_lo * 64;

  float em1d = expm1f(decay);
  float rfE[2]; int iE[2];
  #pragma unroll
  for (int e = 0; e < 2; e++){
    int i = qsE[e] + l15;
    iE[e] = i;
    float rowsum = expm1f((float)(i + 1) * decay) / em1d;
    rfE[e] = __expf((float)(i - k0s) * decay) * rsqrtf(rowsum);
  }
  float e1 = __expf(negd);
  float c16 = __expf(negd * 16.0f);
  float cbr[4];
  cbr[0] = __expf(negd * (float)(quad * 4));
  cbr[1] = cbr[0] * e1; cbr[2] = cbr[1] * e1; cbr[3] = cbr[2] * e1;

  f32x4 o[2][4];
  #pragma unroll
  for (int e = 0; e < 2; e++)
    #pragma unroll
    for (int dt = 0; dt < 4; dt++) o[e][dt] = (f32x4){0.f, 0.f, 0.f, 0.f};
  float babs[2] = {0.f, 0.f};

  const u16* krbh = kr + (size_t)bh * S_LEN * HD;
  const u16* vtbh = vt + (size_t)bh * HD * S_LEN;

  for (int kb = kb_lo; kb <= z_hi; kb++){
    int k0 = kb * 64;
    __syncthreads();
    #pragma unroll
    for (int c = 0; c < 2; c++){
      int L = c * 256 + t;
      gl2lds16(krbh + (size_t)k0 * HD + L * 8, &Ks[L * 8]);
    }
    #pragma unroll
    for (int c = 0; c < 2; c++){
      int L = c * 256 + t;
      gl2lds16(vtbh + (size_t)(L >> 3) * S_LEN + k0 + (L & 7) * 8, &Vs[L * 8]);
    }
    __syncthreads();

    bf16x8 kA0[4], kA1[4];
    #pragma unroll
    for (int ct = 0; ct < 4; ct++){
      int rw = (ct * 16 + l15) * 64;
      kA0[ct] = *(const bf16x8*)&Ks[rw + ((quad ^ h8) * 8)];
      kA1[ct] = *(const bf16x8*)&Ks[rw + (((quad + 4) ^ h8) * 8)];
    }
    #pragma unroll
    for (int e = 0; e < 2; e++){
      int qs = qsE[e];
      if (k0 <= qs + 15 && k0 + 63 >= qs - win_i){
        bool diag = (k0 + 64 > qs);
        float cf[4] = {cbr[0], cbr[1], cbr[2], cbr[3]};
        #pragma unroll
        for (int ct = 0; ct < 4; ct++){
          f32x4 zacc = (f32x4){0.f, 0.f, 0.f, 0.f};
          zacc = __builtin_amdgcn_mfma_f32_16x16x32_bf16(kA0[ct], qB[e][0], zacc, 0, 0, 0);
          zacc = __builtin_amdgcn_mfma_f32_16x16x32_bf16(kA1[ct], qB[e][1], zacc, 0, 0, 0);
          u16 pk[4];
          #pragma unroll
          for (int r = 0; r < 4; r++){
            float p = zacc[r] * (rfE[e] * cf[r]);
            if (diag && (k0 + ct * 16 + quad * 4 + r) > iE[e]) p = 0.f;
            babs[e] += fabsf(p);
            pk[r] = f2bf_fast(p);
            cf[r] *= c16;
          }
          u32 lo = (u32)pk[0] | ((u32)pk[1] << 16);
          u32 hi = (u32)pk[2] | ((u32)pk[3] << 16);
          *(uint2*)&Ps[(rowb[e] + l15) * 72 + ct * 16 + quad * 4] = make_uint2(lo, hi);
        }
      }
    }
    #pragma unroll
    for (int e = 0; e < 2; e++){
      int qs = qsE[e];
      if (k0 <= qs + 15 && k0 + 63 >= qs - win_i){
        bf16x8 pB0 = *(const bf16x8*)&Ps[(rowb[e] + l15) * 72 + quad * 8];
        bf16x8 pB1 = *(const bf16x8*)&Ps[(rowb[e] + l15) * 72 + 32 + quad * 8];
        #pragma unroll
        for (int dt = 0; dt < 4; dt++){
          int rw = (dt * 16 + l15) * 64;
          bf16x8 vA0 = *(const bf16x8*)&Vs[rw + ((quad ^ h8) * 8)];
          bf16x8 vA1 = *(const bf16x8*)&Vs[rw + (((quad + 4) ^ h8) * 8)];
          o[e][dt] = __builtin_amdgcn_mfma_f32_16x16x32_bf16(vA0, pB0, o[e][dt], 0, 0, 0);
          o[e][dt] = __builtin_amdgcn_mfma_f32_16x16x32_bf16(vA1, pB1, o[e][dt], 0, 0, 0);
        }
      }
    }
    #pragma unroll
    for (int e = 0; e < 2; e++) rfE[e] *= estep;
  }

  // partials: pO[slot][dt=4][i=128][dsub=16] bf16, pBa[slot][i=128] bf16
  size_t slot = ((size_t)bh * 16 + qb) * 4 + z;
  u16* po = pO + slot * (4 * 128 * 16);
  #pragma unroll
  for (int e = 0; e < 2; e++){
    float bsum = babs[e];
    bsum += __shfl_xor(bsum, 16);
    bsum += __shfl_xor(bsum, 32);
    if (quad == 0) pBa[slot * 128 + rowb[e] + l15] = f2bf(bsum);
    #pragma unroll
    for (int dt = 0; dt < 4; dt++){
      u16 pk[4];
      #pragma unroll
      for (int r = 0; r < 4; r++) pk[r] = f2bf(o[e][dt][r]);
      *(uint2*)&po[(dt * 128 + rowb[e] + l15) * 16 + quad * 4] = *(uint2*)pk;
    }
  }
}

// ---------------- combine: sum 4 partials, denom clip, RMS, SiLU(g) ----------------
__global__ __launch_bounds__(128) void combine_kernel(const u16* __restrict__ pO, const u16* __restrict__ pBa,
                                                      const u16* __restrict__ gc, float* __restrict__ out){
  int bh = blockIdx.x, qb = blockIdx.y;
  int b = bh >> 4, h = bh & 15;
  int i = threadIdx.x;
  int s = qb * 128 + i;
  size_t s4 = ((size_t)bh * 16 + qb) * 4;
  float v[64];
  #pragma unroll
  for (int d = 0; d < 64; d++) v[d] = 0.f;
  float bsum = 0.f;
  #pragma unroll
  for (int z = 0; z < 4; z++){
    const u16* pz = pO + (s4 + z) * 8192;
    #pragma unroll
    for (int dt = 0; dt < 4; dt++){
      u16 a[16];
      *(uint4*)&a[0] = *(const uint4*)&pz[(dt * 128 + i) * 16];
      *(uint4*)&a[8] = *(const uint4*)&pz[(dt * 128 + i) * 16 + 8];
      #pragma unroll
      for (int c = 0; c < 16; c++) v[dt * 16 + c] += bf2f(a[c]);
    }
    bsum += bf2f(pBa[(s4 + z) * 128 + i]);
  }
  float dinv = 1.0f / fminf(fmaxf(bsum, 1.0f), 50000.0f);
  float ssq = 0.f;
  #pragma unroll
  for (int d = 0; d < 64; d++){ v[d] *= dinv; ssq += v[d] * v[d]; }
  float rms = rsqrtf(ssq * (1.0f / 64.0f) + 1e-6f);
  size_t gbase = ((size_t)b * S_LEN + s) * E_DIM + h * HD;
  u16 gu[64];
  #pragma unroll
  for (int c = 0; c < 8; c++) *(uint4*)&gu[c * 8] = *(const uint4*)&gc[gbase + c * 8];
  float ov[64];
  #pragma unroll
  for (int d = 0; d < 64; d++){
    float gv = bf2f(gu[d]);
    float sg = gv / (1.0f + __expf(-gv));
    ov[d] = v[d] * rms * sg;
  }
  float* obase = out + ((size_t)b * S_LEN + s) * E_DIM + h * HD;
  #pragma unroll
  for (int c = 0; c < 16; c++) *(float4*)&obase[c * 4] = *(float4*)&ov[c * 4];
}

extern "C" void kernel_launch(void* const* d_in, const int* in_sizes, int n_in,
                              void* d_out, int out_size, void* d_ws, size_t ws_size,
                              hipStream_t stream){
  const float* x  = (const float*)d_in[0];
  const float* Wq = (const float*)d_in[1];
  const float* Wk = (const float*)d_in[2];
  const float* Wv = (const float*)d_in[3];
  const float* Wg = (const float*)d_in[4];
  float* out = (float*)d_out;
  char* ws = (char*)d_ws;
  // ws layout (stream-ordered overlays), 64.5 MB total (proven footprint):
  //   [0,24M):  qkv  (gemm out, dead after shift) -> pO bf16 partials [0,32M)
  //   [24,32M): (pO tail only)
  //   [32,40M): xb   (dead after gemm) -> qr
  //   [40,48M): WT   (dead after gemm) -> kr
  //   [48,56M): vt
  //   [56,64M): gc   (live until combine)
  //   [64,64.5M): pBa (bf16)
  u16* qkv = (u16*)(ws);
  u16* pO  = (u16*)(ws);
  u16* xb  = (u16*)(ws + (32ull << 20));
  u16* qrp = (u16*)(ws + (32ull << 20));
  u16* WT  = (u16*)(ws + (40ull << 20));
  u16* krp = (u16*)(ws + (40ull << 20));
  u16* vtp = (u16*)(ws + (48ull << 20));
  u16* gcp = (u16*)(ws + (56ull << 20));
  u16* pBa = (u16*)(ws + (64ull << 20));

  prep_kernel     <<<dim3(16, 16, 8),  256, 0, stream>>>(x, Wq, Wk, Wv, Wg, xb, WT);
  gemm_kernel     <<<dim3(32, 32),     256, 0, stream>>>(xb, WT, qkv, gcp);
  shift_kernel    <<<dim3(32, 32),     256, 0, stream>>>(qkv, qrp, krp, vtp);
  retention_kernel<<<dim3(32, 16, 4),  256, 0, stream>>>(qrp, krp, vtp, pO, pBa);
  combine_kernel  <<<dim3(32, 16),     128, 0, stream>>>(pO, pBa, gcp, out);
}